// Round 1
// baseline (280.590 us; speedup 1.0000x reference)
//
#include <hip/hip_runtime.h>
#include <hip/hip_bf16.h>

#define NB 8
#define NN 256
#define DD 64

// workspace layout (in floats)
#define OFF_WCT   0        // 4096  : WcT[d][k] = 0.5*(Wv2@Ws1)[k][d]
#define OFF_CC    4096     // 64    : cc[d] = 0.5*(bv2@Ws1)[d] + bs1[d]
#define OFF_MZ    4160     // 16    : m[8], Z[8]
#define OFF_SH    4176     // 512   : Sh[b][k] = sum_ij w_ij * h_ij[k]
#define OFF_RS    4688     // 2048  : rowsum[b][i] = sum_j w_ij
#define OFF_UT    6736     // 131072: uT[b][d][i] = 0.25*(v[b,i,:]@Ws1)[d]
#define OFF_SC    137808   // 524288: scores[b][i][j]

// ---------------------------------------------------------------- setup ----
__global__ __launch_bounds__(256) void k_setup(
    const float* __restrict__ values, const float* __restrict__ Wv2,
    const float* __restrict__ Ws1, const float* __restrict__ bv2,
    const float* __restrict__ bs1, float* __restrict__ ws)
{
    int idx = blockIdx.x * 256 + threadIdx.x;
    if (idx < 4096) {
        int d = idx >> 6, k = idx & 63;
        float s = 0.f;
        for (int m = 0; m < 64; m++) s += Wv2[k * 64 + m] * Ws1[m * 64 + d];
        ws[OFF_WCT + d * 64 + k] = 0.5f * s;
    } else if (idx < 4160) {
        int d = idx - 4096;
        float s = 0.f;
        for (int k = 0; k < 64; k++) s += bv2[k] * Ws1[k * 64 + d];
        ws[OFF_CC + d] = 0.5f * s + bs1[d];
    } else if (idx < 4160 + NB * NN * DD) {
        int r = idx - 4160;
        int d = r & 63;
        int bi = r >> 6;             // b*256 + i
        int b = bi >> 8, i = bi & 255;
        const float* v = values + bi * 64;
        float s = 0.f;
        for (int k = 0; k < 64; k++) s += v[k] * Ws1[k * 64 + d];
        ws[OFF_UT + (b * 64 + d) * 256 + i] = 0.25f * s;
    }
}

// ---------------------------------------------------------------- pass1 ----
// grid: 8 batches * 128 row-pairs. block=256 (thread j), 2 rows per block.
__global__ __launch_bounds__(256, 2) void k_pass1(
    const float* __restrict__ pos, const float* __restrict__ Wv1,
    const float* __restrict__ bv1, const float* __restrict__ Ws2,
    float* __restrict__ ws)
{
    __shared__ float lds_wc[4096];       // WcT[d][k]
    __shared__ float4 lds_coef[64];      // {Wv1[0][k], Wv1[1][k], bv1[k], Ws2[k]}
    __shared__ float lds_cui0[64], lds_cui1[64];
    __shared__ float lds_pos[6];

    const float* wcT = ws + OFF_WCT;
    const float* cc  = ws + OFF_CC;
    const float* uT  = ws + OFF_UT;
    float* scores    = ws + OFF_SC;

    int b = blockIdx.x >> 7;
    int i0 = (blockIdx.x & 127) * 2, i1 = i0 + 1;
    int t = threadIdx.x;

    for (int idx = t; idx < 4096; idx += 256) lds_wc[idx] = wcT[idx];
    if (t < 64) {
        lds_coef[t] = make_float4(Wv1[t], Wv1[64 + t], bv1[t], Ws2[t]);
        lds_cui0[t] = cc[t] + uT[(b * 64 + t) * 256 + i0];
        lds_cui1[t] = cc[t] + uT[(b * 64 + t) * 256 + i1];
    }
    if (t < 6) lds_pos[t] = pos[(b * 256 + i0) * 3 + t];
    __syncthreads();

    int j = t;
    float px = pos[(b * 256 + j) * 3 + 0];
    float py = pos[(b * 256 + j) * 3 + 1];
    float pz = pos[(b * 256 + j) * 3 + 2];
    float ax = lds_pos[0], ay = lds_pos[1], az = lds_pos[2];
    float bx = lds_pos[3], by = lds_pos[4], bz = lds_pos[5];

    float dot0 = ax * px + ay * py + az * pz;
    float cx0 = ay * pz - az * py, cy0 = az * px - ax * pz, cz0 = ax * py - ay * px;
    float biv0 = sqrtf(cx0 * cx0 + cy0 * cy0 + cz0 * cz0 + 1e-20f);
    float dot1 = bx * px + by * py + bz * pz;
    float cx1 = by * pz - bz * py, cy1 = bz * px - bx * pz, cz1 = bx * py - by * px;
    float biv1 = sqrtf(cx1 * cx1 + cy1 * cy1 + cz1 * cz1 + 1e-20f);

    float ha[64], hb[64];
#pragma unroll
    for (int k = 0; k < 64; k++) {
        float4 co = lds_coef[k];
        ha[k] = fmaxf(fmaf(dot0, co.x, fmaf(biv0, co.y, co.z)), 0.f);
        hb[k] = fmaxf(fmaf(dot1, co.x, fmaf(biv1, co.y, co.z)), 0.f);
    }

    float sc0 = 0.f, sc1 = 0.f;
    const float* uTb = uT + b * 64 * 256 + j;
    for (int d = 0; d < 64; d++) {
        float ujd = uTb[d * 256];
        float s0 = lds_cui0[d] + ujd;
        float s1 = lds_cui1[d] + ujd;
        const float4* wrow = (const float4*)(lds_wc + d * 64);
#pragma unroll
        for (int k4 = 0; k4 < 16; k4++) {
            float4 w4 = wrow[k4];
            s0 = fmaf(ha[4 * k4 + 0], w4.x, s0); s0 = fmaf(ha[4 * k4 + 1], w4.y, s0);
            s0 = fmaf(ha[4 * k4 + 2], w4.z, s0); s0 = fmaf(ha[4 * k4 + 3], w4.w, s0);
            s1 = fmaf(hb[4 * k4 + 0], w4.x, s1); s1 = fmaf(hb[4 * k4 + 1], w4.y, s1);
            s1 = fmaf(hb[4 * k4 + 2], w4.z, s1); s1 = fmaf(hb[4 * k4 + 3], w4.w, s1);
        }
        float ws2d = lds_coef[d].w;
        sc0 = fmaf(fmaxf(s0, 0.f), ws2d, sc0);
        sc1 = fmaf(fmaxf(s1, 0.f), ws2d, sc1);
    }
    scores[(b * 256 + i0) * 256 + j] = sc0;
    scores[(b * 256 + i1) * 256 + j] = sc1;
}

// --------------------------------------------------------------- reduce ----
__global__ __launch_bounds__(256) void k_reduce(float* __restrict__ ws)
{
    __shared__ float red[256];
    const float* s = ws + OFF_SC + blockIdx.x * (NN * NN);
    int t = threadIdx.x;
    float mx = -3.4e38f;
    for (int idx = t; idx < NN * NN; idx += 256) mx = fmaxf(mx, s[idx]);
    red[t] = mx; __syncthreads();
    for (int off = 128; off > 0; off >>= 1) {
        if (t < off) red[t] = fmaxf(red[t], red[t + off]);
        __syncthreads();
    }
    float m = red[0]; __syncthreads();
    float sum = 0.f;
    for (int idx = t; idx < NN * NN; idx += 256) sum += __expf(s[idx] - m);
    red[t] = sum; __syncthreads();
    for (int off = 128; off > 0; off >>= 1) {
        if (t < off) red[t] = red[t] + red[t + off];
        __syncthreads();
    }
    if (t == 0) { ws[OFF_MZ + blockIdx.x] = m; ws[OFF_MZ + 8 + blockIdx.x] = red[0]; }
}

// ---------------------------------------------------------------- pass2 ----
// one wave per (b,i) row. lane = k (h dimension).
__global__ __launch_bounds__(64) void k_pass2(
    const float* __restrict__ pos, const float* __restrict__ Wv1,
    const float* __restrict__ bv1, float* __restrict__ ws)
{
    int b = blockIdx.x >> 8, i = blockIdx.x & 255;
    int lane = threadIdx.x;
    float A = Wv1[lane], B = Wv1[64 + lane], C = bv1[lane];
    float ax = pos[(b * 256 + i) * 3 + 0];
    float ay = pos[(b * 256 + i) * 3 + 1];
    float az = pos[(b * 256 + i) * 3 + 2];
    float m = ws[OFF_MZ + b];
    const float* srow = ws + OFF_SC + (b * 256 + i) * 256;
    const float* pb = pos + b * 768;
    float acc = 0.f, rs = 0.f;
    for (int j = 0; j < 256; j++) {
        float px = pb[3 * j], py = pb[3 * j + 1], pz = pb[3 * j + 2];
        float dot = ax * px + ay * py + az * pz;
        float cx = ay * pz - az * py, cy = az * px - ax * pz, cz = ax * py - ay * px;
        float biv = sqrtf(cx * cx + cy * cy + cz * cz + 1e-20f);
        float w = __expf(srow[j] - m);
        float h = fmaxf(fmaf(dot, A, fmaf(biv, B, C)), 0.f);
        acc = fmaf(w, h, acc);
        rs += w;
    }
    atomicAdd(&ws[OFF_SH + b * 64 + lane], acc);
    if (lane == 0) ws[OFF_RS + b * 256 + i] = rs;
}

// ------------------------------------------------------------- finalize ----
__global__ __launch_bounds__(64) void k_finalize(
    const float* __restrict__ Wv2, const float* __restrict__ bv2,
    const float* __restrict__ values, const float* __restrict__ ws,
    float* __restrict__ out)
{
    int b = blockIdx.x, d = threadIdx.x;
    __shared__ float sh[64];
    sh[d] = ws[OFF_SH + b * 64 + d];
    __syncthreads();
    float Z = ws[OFF_MZ + 8 + b];
    float t1 = 0.f;
    for (int k = 0; k < 64; k++) t1 = fmaf(sh[k], Wv2[k * 64 + d], t1);
    float acc2 = 0.f;
    const float* rs = ws + OFF_RS + b * 256;
    const float* v = values + b * 256 * 64;
    for (int i = 0; i < 256; i++) acc2 = fmaf(rs[i], v[i * 64 + d], acc2);
    out[b * 64 + d] = 0.5f * (t1 + acc2) / Z + 0.5f * bv2[d];
}

// ---------------------------------------------------------------- launch ---
extern "C" void kernel_launch(void* const* d_in, const int* in_sizes, int n_in,
                              void* d_out, int out_size, void* d_ws, size_t ws_size,
                              hipStream_t stream)
{
    const float* positions = (const float*)d_in[0];
    const float* values    = (const float*)d_in[1];
    const float* Wv1       = (const float*)d_in[2];
    const float* bv1       = (const float*)d_in[3];
    const float* Wv2       = (const float*)d_in[4];
    const float* bv2       = (const float*)d_in[5];
    const float* Ws1       = (const float*)d_in[6];
    const float* bs1       = (const float*)d_in[7];
    const float* Ws2       = (const float*)d_in[8];
    // d_in[9] = bs2: softmax-invariant constant on scores, does not affect output
    float* ws  = (float*)d_ws;
    float* out = (float*)d_out;

    // zero the Sh accumulator (ws is poisoned 0xAA before every launch)
    hipMemsetAsync(ws + OFF_SH, 0, 512 * sizeof(float), stream);

    k_setup<<<529, 256, 0, stream>>>(values, Wv2, Ws1, bv2, bs1, ws);
    k_pass1<<<NB * 128, 256, 0, stream>>>(positions, Wv1, bv1, Ws2, ws);
    k_reduce<<<NB, 256, 0, stream>>>(ws);
    k_pass2<<<NB * NN, 64, 0, stream>>>(positions, Wv1, bv1, ws);
    k_finalize<<<NB, 64, 0, stream>>>(Wv2, bv2, values, ws, out);
}

// Round 2
// 123.331 us; speedup vs baseline: 2.2751x; 2.2751x over previous
//
#include <hip/hip_runtime.h>
#include <hip/hip_bf16.h>

#define NB 8
#define NN 256
#define DD 64

// workspace layout (float offsets)
#define OFF_WCSW  0        // 2048 floats = 4096 bf16: B-fragments of Wc, swizzled [ks][nt][lane][8]
#define OFF_CSA   2048     // 1024 : Wv1 row0 swizzled [ks][lane][8]
#define OFF_CSB   3072     // 1024 : Wv1 row1 swizzled
#define OFF_CSC   4096     // 1024 : bv1 swizzled
#define OFF_CC    5120     // 64   : cc[d] = 0.5*(bv2@Ws1)[d] + bs1[d]
#define OFF_M     5184     // 8    : per-batch max as monotonic-uint keys
#define OFF_RS    5248     // 2048 : rowsum[b][i]
#define OFF_U     7296     // 131072 : u[b][i][d] = 0.25*(v@Ws1)
#define OFF_SC    138368   // 524288 : scores[b][i][j]; after pass2, first 64 of each row hold partial-Sh

typedef __attribute__((ext_vector_type(4))) float f32x4;
typedef __attribute__((ext_vector_type(8))) short s16x8;

static __device__ __forceinline__ unsigned short bf16_rn(float x) {
    unsigned u = __float_as_uint(x);
    u += 0x8000u;                 // round-half-up; inputs finite, fine
    return (unsigned short)(u >> 16);
}

// ---------------------------------------------------------------- setup ----
__global__ __launch_bounds__(256) void k_setup(
    const float* __restrict__ values, const float* __restrict__ Wv1,
    const float* __restrict__ bv1, const float* __restrict__ Wv2,
    const float* __restrict__ bv2, const float* __restrict__ Ws1,
    const float* __restrict__ bs1, float* __restrict__ ws)
{
    int idx = blockIdx.x * 256 + threadIdx.x;
    if (idx < 131072) {
        // u[b][i][d] = 0.25 * (v[b,i,:] @ Ws1)[d]
        int d = idx & 63;
        const float* v = values + (idx >> 6) * 64;
        float s = 0.f;
        for (int k = 0; k < 64; k++) s = fmaf(v[k], Ws1[k * 64 + d], s);
        ws[OFF_U + idx] = 0.25f * s;
    } else if (idx < 135168) {
        // Wc bf16 swizzled into MFMA B-fragment order
        int e = idx - 131072;
        int j = e & 7, lane = (e >> 3) & 63, nt = (e >> 9) & 3, ks = e >> 11;
        int k = ks * 32 + ((lane >> 4) & 3) * 8 + j;
        int d = nt * 16 + (lane & 15);
        float s = 0.f;
        for (int m = 0; m < 64; m++) s = fmaf(Wv2[k * 64 + m], Ws1[m * 64 + d], s);
        ((unsigned short*)(ws + OFF_WCSW))[e] = bf16_rn(0.5f * s);
    } else if (idx < 136192) {
        // h-coefficients swizzled to A-fragment lane order
        int e = idx - 135168;
        int j = e & 7, lane = (e >> 3) & 63, ks = e >> 9;
        int k = ks * 32 + ((lane >> 4) & 3) * 8 + j;
        ws[OFF_CSA + e] = Wv1[k];
        ws[OFF_CSB + e] = Wv1[64 + k];
        ws[OFF_CSC + e] = bv1[k];
    } else if (idx < 136256) {
        int d = idx - 136192;
        float s = 0.f;
        for (int k = 0; k < 64; k++) s = fmaf(bv2[k], Ws1[k * 64 + d], s);
        ws[OFF_CC + d] = 0.5f * s + bs1[d];
    } else if (idx < 136264) {
        ((unsigned*)(ws + OFF_M))[idx - 136256] = 0u;   // min key
    }
}

// ---------------------------------------------------------------- pass1 ----
// grid: 8 batches * 128 i-tiles (TI=2 rows each). block = 256 (4 waves).
// Wave w covers j in [w*64, w*64+64). MFMA GEMM: S(pairs x 64) = H @ Wc.
__global__ __launch_bounds__(256, 2) void k_pass1(
    const float* __restrict__ pos, const float* __restrict__ Ws2,
    float* __restrict__ ws)
{
    __shared__ float2 ldsDB[2 * 256];   // (dot, biv) per (ii, j)
    __shared__ float  ldsCCU[2 * 64];   // cc[d] + u[i][d]
    __shared__ float  ldsWs2[64];
    __shared__ float  ldsPos[6];
    __shared__ float  ldsRed[256];

    int b  = blockIdx.x >> 7;
    int i0 = (blockIdx.x & 127) * 2;
    int t  = threadIdx.x;
    const float* uB = ws + OFF_U + b * (NN * DD);

    if (t < 6)  ldsPos[t] = pos[(b * 256 + i0) * 3 + t];
    if (t < 64) ldsWs2[t] = Ws2[t];
    if (t < 128) {
        int ii = t >> 6, d = t & 63;
        ldsCCU[t] = ws[OFF_CC + d] + uB[(i0 + ii) * 64 + d];
    }
    __syncthreads();

    {   // dot/biv precompute: thread t = column j
        float px = pos[(b * 256 + t) * 3 + 0];
        float py = pos[(b * 256 + t) * 3 + 1];
        float pz = pos[(b * 256 + t) * 3 + 2];
#pragma unroll
        for (int ii = 0; ii < 2; ii++) {
            float ax = ldsPos[ii * 3 + 0], ay = ldsPos[ii * 3 + 1], az = ldsPos[ii * 3 + 2];
            float dot = ax * px + ay * py + az * pz;
            float cx = ay * pz - az * py;
            float cy = az * px - ax * pz;
            float cz = ax * py - ay * px;
            float biv = sqrtf(cx * cx + cy * cy + cz * cz + 1e-20f);
            ldsDB[ii * 256 + t] = make_float2(dot, biv);
        }
    }
    __syncthreads();

    int lane = t & 63, w = t >> 6;
    int q = lane >> 4, col = lane & 15;

    // h coefficients for this lane's 16 k-slots (registers)
    float cA[16], cB[16], cC[16];
    {
        const f32x4* pa0 = (const f32x4*)(ws + OFF_CSA + lane * 8);
        const f32x4* pa1 = (const f32x4*)(ws + OFF_CSA + 512 + lane * 8);
        ((f32x4*)cA)[0] = pa0[0]; ((f32x4*)cA)[1] = pa0[1];
        ((f32x4*)cA)[2] = pa1[0]; ((f32x4*)cA)[3] = pa1[1];
        const f32x4* pb0 = (const f32x4*)(ws + OFF_CSB + lane * 8);
        const f32x4* pb1 = (const f32x4*)(ws + OFF_CSB + 512 + lane * 8);
        ((f32x4*)cB)[0] = pb0[0]; ((f32x4*)cB)[1] = pb0[1];
        ((f32x4*)cB)[2] = pb1[0]; ((f32x4*)cB)[3] = pb1[1];
        const f32x4* pc0 = (const f32x4*)(ws + OFF_CSC + lane * 8);
        const f32x4* pc1 = (const f32x4*)(ws + OFF_CSC + 512 + lane * 8);
        ((f32x4*)cC)[0] = pc0[0]; ((f32x4*)cC)[1] = pc0[1];
        ((f32x4*)cC)[2] = pc1[0]; ((f32x4*)cC)[3] = pc1[1];
    }

    // Wc B-fragments (registers, block-invariant)
    s16x8 bf[2][4];
    {
        const s16x8* wsw = (const s16x8*)(ws + OFF_WCSW);
#pragma unroll
        for (int ks = 0; ks < 2; ks++)
#pragma unroll
            for (int nt = 0; nt < 4; nt++)
                bf[ks][nt] = wsw[(ks * 4 + nt) * 64 + lane];
    }

    float wmax = -3.4e38f;
    float* scrow_base = ws + OFF_SC + (b * 256 + i0) * 256;

#pragma unroll
    for (int jt4 = 0; jt4 < 4; jt4++) {
        int jt = w * 4 + jt4;
        // cache u_j for this j16 tile: [r][nt]
        float uc[4][4];
#pragma unroll
        for (int r = 0; r < 4; r++) {
            int jl = jt * 16 + q * 4 + r;
#pragma unroll
            for (int nt = 0; nt < 4; nt++)
                uc[r][nt] = uB[jl * 64 + nt * 16 + col];
        }
#pragma unroll
        for (int ii = 0; ii < 2; ii++) {
            float2 db = ldsDB[ii * 256 + jt * 16 + col];
            // A-fragments: h = relu(A*dot + B*biv + C), cast bf16
            s16x8 af[2];
#pragma unroll
            for (int ks = 0; ks < 2; ks++)
#pragma unroll
                for (int j = 0; j < 8; j++) {
                    float h = fmaf(db.x, cA[ks * 8 + j], fmaf(db.y, cB[ks * 8 + j], cC[ks * 8 + j]));
                    af[ks][j] = (short)bf16_rn(fmaxf(h, 0.f));
                }
            f32x4 acc[4];
#pragma unroll
            for (int nt = 0; nt < 4; nt++) acc[nt] = (f32x4){0.f, 0.f, 0.f, 0.f};
#pragma unroll
            for (int nt = 0; nt < 4; nt++) {
                acc[nt] = __builtin_amdgcn_mfma_f32_16x16x32_bf16(af[0], bf[0][nt], acc[nt], 0, 0, 0);
                acc[nt] = __builtin_amdgcn_mfma_f32_16x16x32_bf16(af[1], bf[1][nt], acc[nt], 0, 0, 0);
            }
            // epilogue: + cc + u_i + u_j, relu, *Ws2, reduce over d
            float tr[4] = {0.f, 0.f, 0.f, 0.f};
#pragma unroll
            for (int nt = 0; nt < 4; nt++) {
                float cu = ldsCCU[ii * 64 + nt * 16 + col];
                float w2 = ldsWs2[nt * 16 + col];
#pragma unroll
                for (int r = 0; r < 4; r++) {
                    float s = acc[nt][r] + cu + uc[r][nt];
                    tr[r] = fmaf(fmaxf(s, 0.f), w2, tr[r]);
                }
            }
#pragma unroll
            for (int m = 1; m < 16; m <<= 1) {
#pragma unroll
                for (int r = 0; r < 4; r++) tr[r] += __shfl_xor(tr[r], m);
            }
            wmax = fmaxf(wmax, fmaxf(fmaxf(tr[0], tr[1]), fmaxf(tr[2], tr[3])));
            if (col == 0) {
                float4 sc4 = make_float4(tr[0], tr[1], tr[2], tr[3]);
                *(float4*)(scrow_base + ii * 256 + jt * 16 + q * 4) = sc4;
            }
        }
    }

    // block max -> global atomic (order-encoded uint)
    ldsRed[t] = wmax;
    __syncthreads();
    for (int off = 128; off > 0; off >>= 1) {
        if (t < off) ldsRed[t] = fmaxf(ldsRed[t], ldsRed[t + off]);
        __syncthreads();
    }
    if (t == 0) {
        unsigned bits = __float_as_uint(ldsRed[0]);
        unsigned key = (bits & 0x80000000u) ? ~bits : (bits | 0x80000000u);
        atomicMax((unsigned*)(ws + OFF_M) + b, key);
    }
}

// ---------------------------------------------------------------- pass2 ----
// one block (256 thr) per (b,i) row: w_j = exp(s-m); Sh_partial[k] = sum_j w_j h_ij[k]
__global__ __launch_bounds__(256) void k_pass2(
    const float* __restrict__ pos, const float* __restrict__ Wv1,
    const float* __restrict__ bv1, float* __restrict__ ws)
{
    __shared__ float  ldsW[256];
    __shared__ float2 ldsDB[256];
    __shared__ float  ldsP[4][64];
    __shared__ float  ldsRed[256];

    int b = blockIdx.x >> 8, i = blockIdx.x & 255;
    int t = threadIdx.x;

    unsigned key = ((const unsigned*)(ws + OFF_M))[b];
    unsigned mbits = (key & 0x80000000u) ? (key ^ 0x80000000u) : ~key;
    float m = __uint_as_float(mbits);

    float* srow = ws + OFF_SC + (b * 256 + i) * 256;
    float wgt = __expf(srow[t] - m);
    ldsW[t] = wgt;
    {
        float ax = pos[(b * 256 + i) * 3 + 0];
        float ay = pos[(b * 256 + i) * 3 + 1];
        float az = pos[(b * 256 + i) * 3 + 2];
        float px = pos[(b * 256 + t) * 3 + 0];
        float py = pos[(b * 256 + t) * 3 + 1];
        float pz = pos[(b * 256 + t) * 3 + 2];
        float dot = ax * px + ay * py + az * pz;
        float cx = ay * pz - az * py;
        float cy = az * px - ax * pz;
        float cz = ax * py - ay * px;
        float biv = sqrtf(cx * cx + cy * cy + cz * cz + 1e-20f);
        ldsDB[t] = make_float2(dot, biv);
    }
    ldsRed[t] = wgt;
    __syncthreads();
    for (int off = 128; off > 0; off >>= 1) {
        if (t < off) ldsRed[t] += ldsRed[t + off];
        __syncthreads();
    }
    if (t == 0) ws[OFF_RS + b * 256 + i] = ldsRed[0];

    int g = t >> 6, k = t & 63;
    float A = Wv1[k], B = Wv1[64 + k], C = bv1[k];
    float acc = 0.f;
#pragma unroll 4
    for (int jj = 0; jj < 64; jj++) {
        int j = g * 64 + jj;
        float2 db = ldsDB[j];
        float h = fmaxf(fmaf(db.x, A, fmaf(db.y, B, C)), 0.f);
        acc = fmaf(ldsW[j], h, acc);
    }
    ldsP[g][k] = acc;
    __syncthreads();
    // write partial Sh into the (now dead) first 64 floats of this score row
    if (t < 64) srow[t] = ldsP[0][t] + ldsP[1][t] + ldsP[2][t] + ldsP[3][t];
}

// ------------------------------------------------------------- finalize ----
__global__ __launch_bounds__(256) void k_finalize(
    const float* __restrict__ values, const float* __restrict__ Wv2,
    const float* __restrict__ bv2, const float* __restrict__ ws,
    float* __restrict__ out)
{
    __shared__ float ldsRS[256], P1[4][64], P2[4][64], Sh[64];
    int b = blockIdx.x, t = threadIdx.x, g = t >> 6, x = t & 63;

    ldsRS[t] = ws[OFF_RS + b * 256 + t];
    const float* phb = ws + OFF_SC + b * (NN * NN);
    float shp = 0.f;
    for (int i = g * 64; i < g * 64 + 64; i++) shp += phb[i * 256 + x];
    P1[g][x] = shp;
    __syncthreads();
    if (t < 64) Sh[x] = P1[0][x] + P1[1][x] + P1[2][x] + P1[3][x];
    __syncthreads();

    float t1p = 0.f;
    for (int k = g * 16; k < g * 16 + 16; k++) t1p = fmaf(Sh[k], Wv2[k * 64 + x], t1p);
    float a2p = 0.f;
    const float* vb = values + b * (NN * DD);
    for (int i = g * 64; i < g * 64 + 64; i++) a2p = fmaf(ldsRS[i], vb[i * 64 + x], a2p);
    P1[g][x] = t1p; P2[g][x] = a2p;
    __syncthreads();

    if (t < 64) {
        float zp = ldsRS[x] + ldsRS[64 + x] + ldsRS[128 + x] + ldsRS[192 + x];
#pragma unroll
        for (int md = 32; md; md >>= 1) zp += __shfl_xor(zp, md);
        float t1 = P1[0][x] + P1[1][x] + P1[2][x] + P1[3][x];
        float a2 = P2[0][x] + P2[1][x] + P2[2][x] + P2[3][x];
        out[b * 64 + x] = 0.5f * (t1 + a2) / zp + 0.5f * bv2[x];
    }
}

// ---------------------------------------------------------------- launch ---
extern "C" void kernel_launch(void* const* d_in, const int* in_sizes, int n_in,
                              void* d_out, int out_size, void* d_ws, size_t ws_size,
                              hipStream_t stream)
{
    const float* positions = (const float*)d_in[0];
    const float* values    = (const float*)d_in[1];
    const float* Wv1       = (const float*)d_in[2];
    const float* bv1       = (const float*)d_in[3];
    const float* Wv2       = (const float*)d_in[4];
    const float* bv2       = (const float*)d_in[5];
    const float* Ws1       = (const float*)d_in[6];
    const float* bs1       = (const float*)d_in[7];
    const float* Ws2       = (const float*)d_in[8];
    // d_in[9] = bs2: uniform shift on scores, cancels in softmax
    float* ws  = (float*)d_ws;
    float* out = (float*)d_out;

    k_setup<<<533, 256, 0, stream>>>(values, Wv1, bv1, Wv2, bv2, Ws1, bs1, ws);
    k_pass1<<<1024, 256, 0, stream>>>(positions, Ws2, ws);
    k_pass2<<<2048, 256, 0, stream>>>(positions, Wv1, bv1, ws);
    k_finalize<<<NB, 256, 0, stream>>>(values, Wv2, bv2, ws, out);
}